// Round 8
// baseline (1698.156 us; speedup 1.0000x reference)
//
#include <hip/hip_runtime.h>

#define D 128
#define N_ITER 40
#define DW (D / 2)   // 64 packed-bf16 words per row

struct Ent8 { int c; float w; };

// flags[0]: edges 32-bit  [1]: mask odd word nz  [2]: mask word>1
// [3]: mask halfword non-float-like  [4]: mask low-halfword float-like
// [6]: x-is-bf16 votes (of 4096)  [7]: unmasked row count
// [9]: masked-col entry total      [10]: unmasked-col entry total
__device__ __forceinline__ int r8_mask_mode(const int* f) {
    if (!f[2]) return f[1] ? 1 : 2;
    if (!f[3]) return f[4] ? 3 : 1;
    return 0;
}
__device__ __forceinline__ bool r8_get_mask(const void* m, int i, int mode) {
    if (mode == 2) return ((const unsigned int*)m)[2 * (long long)i] != 0u;
    if (mode == 1) return ((const unsigned int*)m)[i] != 0u;
    if (mode == 3) return ((const unsigned short*)m)[i] != 0u;
    return ((const unsigned char*)m)[i] != 0u;
}
__device__ __forceinline__ int r8_xbf(const int* f) { return (f[6] * 2 >= 4096) ? 1 : 0; }
__device__ __forceinline__ int r8_erow(const int* e32, int e, int i, int is64) {
    return is64 ? e32[2 * (long long)i] : e32[i];
}
__device__ __forceinline__ int r8_ecol(const int* e32, int e, int i, int is64) {
    return is64 ? e32[2 * ((long long)e + i)] : e32[(long long)e + i];
}
__device__ __forceinline__ unsigned short r8_f2bf(float f) {
    unsigned int u = __float_as_uint(f);
    unsigned int r = 0x7fffu + ((u >> 16) & 1u);
    return (unsigned short)((u + r) >> 16);
}
__device__ __forceinline__ int r8_bf16ish(unsigned int h) {
    if (h == 0u) return 1;
    unsigned int ex = (h >> 7) & 0xFFu;
    return (ex >= 100u && ex <= 140u) ? 1 : 0;
}
__device__ __forceinline__ float r8_lo(unsigned int v) { return __uint_as_float(v << 16); }
__device__ __forceinline__ float r8_hi(unsigned int v) { return __uint_as_float(v & 0xFFFF0000u); }
__device__ __forceinline__ unsigned int r8_pack(float a, float b) {
    return (unsigned int)r8_f2bf(a) | ((unsigned int)r8_f2bf(b) << 16);
}
__device__ __forceinline__ long long r8_bidx(int row, int lane, int xbf) {
    return xbf ? ((long long)row * DW + lane) : ((long long)row * D + lane);
}

__global__ void r8_zero(int* p, long long cnt) {
    long long t = (long long)blockIdx.x * blockDim.x + threadIdx.x;
    long long st = (long long)gridDim.x * blockDim.x;
    for (; t < cnt; t += st) p[t] = 0;
}

__global__ void r8_detect(const int* __restrict__ edges, int e,
                          const unsigned int* __restrict__ mask, int n,
                          const unsigned int* __restrict__ x, int* __restrict__ flags) {
    __shared__ int sh_votes;
    if (threadIdx.x == 0) sh_votes = 0;
    __syncthreads();
    int t = blockIdx.x * blockDim.x + threadIdx.x;
    int stride = gridDim.x * blockDim.x;
    int f_e32 = 0, f_odd = 0, f_01 = 0, f_hw = 0, f_h0 = 0;
    for (int i = t; i < 65536; i += stride) {
        long long j = ((long long)i * e) >> 16;
        if (edges[2 * j + 1] != 0) f_e32 = 1;
    }
    int mw = n >> 2;
    for (int i = t; i < mw; i += stride) {
        unsigned int w = mask[i];
        if ((i & 1) && w) f_odd = 1;
        if (w > 1u) f_01 = 1;
        unsigned int h0 = w & 0xFFFFu, h1 = w >> 16;
        if ((h0 && h0 != 0x3F80u && h0 != 0x3C00u) ||
            (h1 && h1 != 0x3F80u && h1 != 0x3C00u)) f_hw = 1;
        if (h0 == 0x3F80u || h0 == 0x3C00u) f_h0 = 1;
    }
    long long xw = (long long)n * DW;
    int my = 0;
    for (int s = t; s < 4096; s += stride) {
        long long j = ((long long)s * xw) >> 12;
        unsigned int w = x[j];
        if (r8_bf16ish(w & 0xFFFFu) && r8_bf16ish(w >> 16)) my++;
    }
    if (my) atomicAdd(&sh_votes, my);
    if (f_e32) atomicOr(&flags[0], 1);
    if (f_odd) atomicOr(&flags[1], 1);
    if (f_01)  atomicOr(&flags[2], 1);
    if (f_hw)  atomicOr(&flags[3], 1);
    if (f_h0)  atomicOr(&flags[4], 1);
    __syncthreads();
    if (threadIdx.x == 0 && sh_votes) atomicAdd(&flags[6], sh_votes);
}

// exactly 1 atomic per edge: masked row -> deg; unmasked row -> packed cnt
// cnt[r]: high16 = masked-col count, low16 = unmasked-col count
__global__ void r8_deg_all(const int* __restrict__ edges, int e,
                           const void* __restrict__ mask, int* __restrict__ deg,
                           int* __restrict__ cnt, const int* __restrict__ flags) {
    int i = blockIdx.x * blockDim.x + threadIdx.x;
    if (i >= e) return;
    int is64 = (flags[0] == 0);
    int mm = r8_mask_mode(flags);
    int r = r8_erow(edges, e, i, is64);
    if (r8_get_mask(mask, r, mm)) { atomicAdd(&deg[r], 1); return; }
    int c = r8_ecol(edges, e, i, is64);
    atomicAdd(&cnt[r], r8_get_mask(mask, c, mm) ? 0x10000 : 1);
}

// dinv for all nodes + unmasked count + degree histogram (descending bins)
__global__ void r8_rows(const int* __restrict__ deg, const int* __restrict__ cnt,
                        float* __restrict__ dinv, int* __restrict__ dhist,
                        const void* __restrict__ mask, int* __restrict__ flags, int n) {
    int i = blockIdx.x * blockDim.x + threadIdx.x;
    if (i >= n) return;
    int mm = r8_mask_mode(flags);
    bool m = r8_get_mask(mask, i, mm);
    int d;
    if (m) d = deg[i];
    else { int p = cnt[i]; d = (p >> 16) + (p & 0xFFFF); }
    dinv[i] = (d > 0) ? (1.0f / sqrtf((float)d)) : 0.0f;
    if (!m) {
        atomicAdd(&flags[7], 1);
        int cu = cnt[i] & 0xFFFF;
        int bin = (cu > 63) ? 0 : (63 - cu);
        atomicAdd(&dhist[bin], 1);
    }
}

__global__ void r8_binoff(const int* __restrict__ dhist, int* __restrict__ boff) {
    if (threadIdx.x == 0) {
        int t = 0;
        for (int b = 0; b < 64; ++b) { boff[b] = t; t += dhist[b]; }
    }
}

// fused: entry offsets + degree-sorted meta (meta[pos] = {row, start_u, cnt_u, 0})
__global__ void r8_scatter(const int* __restrict__ cnt, int* __restrict__ start_m,
                           int* __restrict__ start_u, const int* __restrict__ boff,
                           int* __restrict__ bcur, int4* __restrict__ meta,
                           const void* __restrict__ mask, int* __restrict__ flags, int n) {
    int i = blockIdx.x * blockDim.x + threadIdx.x;
    if (i >= n) return;
    int mm = r8_mask_mode(flags);
    if (r8_get_mask(mask, i, mm)) return;
    int p = cnt[i];
    int cm = p >> 16, cu = p & 0xFFFF;
    int sm = atomicAdd(&flags[9], cm);
    int su = atomicAdd(&flags[10], cu);
    start_m[i] = sm;
    start_u[i] = su;
    int bin = (cu > 63) ? 0 : (63 - cu);
    int pos = boff[bin] + atomicAdd(&bcur[bin], 1);
    int4 mu; mu.x = i; mu.y = su; mu.z = cu; mu.w = 0;
    meta[pos] = mu;
}

__global__ void r8_fill(const int* __restrict__ edges, int e, const float* __restrict__ dinv,
                        const int* __restrict__ start_m, const int* __restrict__ start_u,
                        unsigned int* __restrict__ cur,
                        Ent8* __restrict__ ents_m, Ent8* __restrict__ ents_u,
                        const void* __restrict__ mask, const int* __restrict__ flags) {
    int i = blockIdx.x * blockDim.x + threadIdx.x;
    if (i >= e) return;
    int is64 = (flags[0] == 0);
    int mm = r8_mask_mode(flags);
    int r = r8_erow(edges, e, i, is64);
    if (r8_get_mask(mask, r, mm)) return;
    int c = r8_ecol(edges, e, i, is64);
    Ent8 en; en.c = c; en.w = dinv[r] * dinv[c];
    bool cmask = r8_get_mask(mask, c, mm);
    unsigned int ret = atomicAdd(&cur[r], cmask ? 0x10000u : 1u);
    if (cmask) ents_m[start_m[r] + (ret >> 16)] = en;
    else       ents_u[start_u[r] + (ret & 0xFFFFu)] = en;
}

// init: masked rows = x into A, B, and d_out; unmasked rows of A/B = 0
__global__ void r8_init(const void* __restrict__ x, const void* __restrict__ mask,
                        unsigned int* __restrict__ A, unsigned int* __restrict__ B,
                        void* __restrict__ out, int n, const int* __restrict__ flags) {
    int t = blockIdx.x * blockDim.x + threadIdx.x;
    if (t >= n * DW) return;
    int node = t >> 6;
    int mm = r8_mask_mode(flags);
    int xbf = r8_xbf(flags);
    bool m = r8_get_mask(mask, node, mm);
    unsigned int w = 0u;
    float2 f = make_float2(0.f, 0.f);
    if (m) {
        if (xbf) w = ((const unsigned int*)x)[t];
        else { f = ((const float2*)x)[t]; w = r8_pack(f.x, f.y); }
    }
    A[t] = w;
    B[t] = w;
    if (m) {
        if (xbf) ((unsigned int*)out)[t] = w;
        else     ((float2*)out)[t] = f;
    }
}

__device__ __forceinline__ void r8_g4(const unsigned int* __restrict__ src,
                                      const Ent8* __restrict__ ep, int i, int lane,
                                      float& ax, float& ay) {
    Ent8 a = ep[i], b = ep[i + 1], c = ep[i + 2], d = ep[i + 3];
    unsigned int va = src[(long long)a.c * DW + lane];
    unsigned int vb = src[(long long)b.c * DW + lane];
    unsigned int vc = src[(long long)c.c * DW + lane];
    unsigned int vd = src[(long long)d.c * DW + lane];
    ax = fmaf(a.w, r8_lo(va), ax); ay = fmaf(a.w, r8_hi(va), ay);
    ax = fmaf(b.w, r8_lo(vb), ax); ay = fmaf(b.w, r8_hi(vb), ay);
    ax = fmaf(c.w, r8_lo(vc), ax); ay = fmaf(c.w, r8_hi(vc), ay);
    ax = fmaf(d.w, r8_lo(vd), ax); ay = fmaf(d.w, r8_hi(vd), ay);
}
__device__ __forceinline__ void r8_g1(const unsigned int* __restrict__ src,
                                      const Ent8* __restrict__ ep, int i, int lane,
                                      float& ax, float& ay) {
    Ent8 a = ep[i];
    unsigned int va = src[(long long)a.c * DW + lane];
    ax = fmaf(a.w, r8_lo(va), ax); ay = fmaf(a.w, r8_hi(va), ay);
}

// one-time base into d_out's unmasked-row slots (dead until final iteration)
__global__ __launch_bounds__(256) void r8_base(
        const void* __restrict__ x, void* __restrict__ out,
        const Ent8* __restrict__ ents_m, const int4* __restrict__ meta,
        const int* __restrict__ start_m, const int* __restrict__ cnt,
        const int* __restrict__ flags) {
    int wi = (blockIdx.x * blockDim.x + threadIdx.x) >> 6;
    int lane = threadIdx.x & 63;
    if (wi >= flags[7]) return;
    wi = __builtin_amdgcn_readfirstlane(wi);
    int row = __builtin_amdgcn_readfirstlane(meta[wi].x);
    int s   = __builtin_amdgcn_readfirstlane(start_m[row]);
    int cm  = __builtin_amdgcn_readfirstlane(cnt[row]) >> 16;
    int xbf = r8_xbf(flags);
    float ax = 0.f, ay = 0.f;
    const Ent8* ep = ents_m + s;
    if (xbf) {
        const unsigned int* src = (const unsigned int*)x;
        int i = 0;
        for (; i + 4 <= cm; i += 4) r8_g4(src, ep, i, lane, ax, ay);
        for (; i < cm; ++i)         r8_g1(src, ep, i, lane, ax, ay);
    } else {
        const float2* xf = (const float2*)x;
        for (int i = 0; i < cm; ++i) {
            Ent8 en = ep[i];
            float2 v = xf[(long long)en.c * DW + lane];
            ax = fmaf(en.w, v.x, ax); ay = fmaf(en.w, v.y, ay);
        }
    }
    ((unsigned int*)out)[r8_bidx(row, lane, xbf)] = r8_pack(ax, ay);
}

// propagation: one wave = FOUR degree-sorted rows, 4x4 interleaved gathers
__global__ __launch_bounds__(256) void r8_prop(
        const unsigned int* __restrict__ src, unsigned int* __restrict__ dst,
        const void* __restrict__ outbase, const Ent8* __restrict__ ents,
        const int4* __restrict__ meta, const int* __restrict__ flags) {
    int wp = (blockIdx.x * blockDim.x + threadIdx.x) >> 6;
    int lane = threadIdx.x & 63;
    int nr = flags[7];
    if (4 * wp >= nr) return;
    wp = __builtin_amdgcn_readfirstlane(wp);
    int i0 = 4 * wp;
    int nv = nr - i0; if (nv > 4) nv = 4;
    int xbf = r8_xbf(flags);
    int rows[4], cc[4];
    const Ent8* ep[4];
    #pragma unroll
    for (int k = 0; k < 4; ++k) {
        if (k < nv) {
            int4 m = meta[i0 + k];
            rows[k] = __builtin_amdgcn_readfirstlane(m.x);
            ep[k]   = ents + __builtin_amdgcn_readfirstlane(m.y);
            cc[k]   = __builtin_amdgcn_readfirstlane(m.z);
        } else { rows[k] = rows[0]; ep[k] = ents; cc[k] = 0; }
    }
    const unsigned int* bp = (const unsigned int*)outbase;
    float ax[4], ay[4];
    #pragma unroll
    for (int k = 0; k < 4; ++k) {
        if (k < nv) {
            unsigned int b = bp[r8_bidx(rows[k], lane, xbf)];
            ax[k] = r8_lo(b); ay[k] = r8_hi(b);
        } else { ax[k] = 0.f; ay[k] = 0.f; }
    }
    int cmin = cc[0];
    #pragma unroll
    for (int k = 1; k < 4; ++k) if (cc[k] < cmin) cmin = cc[k];
    int i = 0;
    for (; i + 4 <= cmin; i += 4) {
        r8_g4(src, ep[0], i, lane, ax[0], ay[0]);
        r8_g4(src, ep[1], i, lane, ax[1], ay[1]);
        r8_g4(src, ep[2], i, lane, ax[2], ay[2]);
        r8_g4(src, ep[3], i, lane, ax[3], ay[3]);
    }
    #pragma unroll
    for (int k = 0; k < 4; ++k) {
        int j = i;
        for (; j + 4 <= cc[k]; j += 4) r8_g4(src, ep[k], j, lane, ax[k], ay[k]);
        for (; j < cc[k]; ++j)         r8_g1(src, ep[k], j, lane, ax[k], ay[k]);
    }
    #pragma unroll
    for (int k = 0; k < 4; ++k)
        if (k < nv) dst[(long long)rows[k] * DW + lane] = r8_pack(ax[k], ay[k]);
}

__global__ __launch_bounds__(256) void r8_prop_final(
        const unsigned int* __restrict__ src, void* __restrict__ out,
        const Ent8* __restrict__ ents, const int4* __restrict__ meta,
        const int* __restrict__ flags) {
    int wp = (blockIdx.x * blockDim.x + threadIdx.x) >> 6;
    int lane = threadIdx.x & 63;
    int nr = flags[7];
    if (4 * wp >= nr) return;
    wp = __builtin_amdgcn_readfirstlane(wp);
    int i0 = 4 * wp;
    int nv = nr - i0; if (nv > 4) nv = 4;
    int xbf = r8_xbf(flags);
    int rows[4], cc[4];
    const Ent8* ep[4];
    #pragma unroll
    for (int k = 0; k < 4; ++k) {
        if (k < nv) {
            int4 m = meta[i0 + k];
            rows[k] = __builtin_amdgcn_readfirstlane(m.x);
            ep[k]   = ents + __builtin_amdgcn_readfirstlane(m.y);
            cc[k]   = __builtin_amdgcn_readfirstlane(m.z);
        } else { rows[k] = rows[0]; ep[k] = ents; cc[k] = 0; }
    }
    const unsigned int* bp = (const unsigned int*)out;
    float ax[4], ay[4];
    #pragma unroll
    for (int k = 0; k < 4; ++k) {
        if (k < nv) {
            unsigned int b = bp[r8_bidx(rows[k], lane, xbf)];
            ax[k] = r8_lo(b); ay[k] = r8_hi(b);
        } else { ax[k] = 0.f; ay[k] = 0.f; }
    }
    int cmin = cc[0];
    #pragma unroll
    for (int k = 1; k < 4; ++k) if (cc[k] < cmin) cmin = cc[k];
    int i = 0;
    for (; i + 4 <= cmin; i += 4) {
        r8_g4(src, ep[0], i, lane, ax[0], ay[0]);
        r8_g4(src, ep[1], i, lane, ax[1], ay[1]);
        r8_g4(src, ep[2], i, lane, ax[2], ay[2]);
        r8_g4(src, ep[3], i, lane, ax[3], ay[3]);
    }
    #pragma unroll
    for (int k = 0; k < 4; ++k) {
        int j = i;
        for (; j + 4 <= cc[k]; j += 4) r8_g4(src, ep[k], j, lane, ax[k], ay[k]);
        for (; j < cc[k]; ++j)         r8_g1(src, ep[k], j, lane, ax[k], ay[k]);
    }
    if (xbf) {
        #pragma unroll
        for (int k = 0; k < 4; ++k)
            if (k < nv)
                ((unsigned int*)out)[(long long)rows[k] * DW + lane] = r8_pack(ax[k], ay[k]);
    } else {
        #pragma unroll
        for (int k = 0; k < 4; ++k)
            if (k < nv) {
                float2 f; f.x = ax[k]; f.y = ay[k];
                ((float2*)out)[(long long)rows[k] * DW + lane] = f;
            }
    }
}

extern "C" void kernel_launch(void* const* d_in, const int* in_sizes, int n_in,
                              void* d_out, int out_size, void* d_ws, size_t ws_size,
                              hipStream_t stream) {
    const void* x    = d_in[0];
    const int* edges = (const int*)d_in[1];
    const void* mask = d_in[2];
    int n = in_sizes[0] / D;
    int e = in_sizes[1] / 2;

    // ---- workspace carve (~80 MiB at n=1e5, e=1.6e6; 100.3 MiB proven to fit) ----
    char* ws = (char*)d_ws;
    size_t off = 0;
    // zero region: flags(64) dhist(64) boff(64) bcur(64) deg(n) cnt(n) cur(n)
    int* flags = (int*)(ws + off); off += 64 * sizeof(int);
    int* dhist = (int*)(ws + off); off += 64 * sizeof(int);
    int* boff  = (int*)(ws + off); off += 64 * sizeof(int);
    int* bcur  = (int*)(ws + off); off += 64 * sizeof(int);
    int* deg   = (int*)(ws + off); off += (size_t)n * sizeof(int);
    int* cnt   = (int*)(ws + off); off += (size_t)n * sizeof(int);
    unsigned int* cur = (unsigned int*)(ws + off); off += (size_t)n * sizeof(int);
    long long zcount = 3LL * n + 256;
    int* start_m = (int*)(ws + off);   off += (size_t)n * sizeof(int);
    int* start_u = (int*)(ws + off);   off += (size_t)n * sizeof(int);
    float* dinv  = (float*)(ws + off); off += (size_t)n * sizeof(float);
    off = (off + 255) & ~(size_t)255;
    int4* meta   = (int4*)(ws + off);  off += (size_t)n * sizeof(int4);
    Ent8* ents_m = (Ent8*)(ws + off);  off += (size_t)e * sizeof(Ent8);
    off = (off + 255) & ~(size_t)255;
    Ent8* ents_u = (Ent8*)(ws + off);  off += (size_t)e * sizeof(Ent8);
    off = (off + 255) & ~(size_t)255;
    size_t hbytes = (size_t)n * D * 2;
    unsigned int* A = (unsigned int*)(ws + off); off += hbytes;
    unsigned int* B = (unsigned int*)(ws + off); off += hbytes;

    r8_zero<<<256, 256, 0, stream>>>(flags, zcount);
    r8_detect<<<128, 256, 0, stream>>>(edges, e, (const unsigned int*)mask, n,
                                       (const unsigned int*)x, flags);
    r8_deg_all<<<(e + 255) / 256, 256, 0, stream>>>(edges, e, mask, deg, cnt, flags);
    r8_rows<<<(n + 255) / 256, 256, 0, stream>>>(deg, cnt, dinv, dhist, mask, flags, n);
    r8_binoff<<<1, 64, 0, stream>>>(dhist, boff);
    r8_scatter<<<(n + 255) / 256, 256, 0, stream>>>(cnt, start_m, start_u, boff, bcur,
                                                    meta, mask, flags, n);
    r8_fill<<<(e + 255) / 256, 256, 0, stream>>>(edges, e, dinv, start_m, start_u,
                                                 cur, ents_m, ents_u, mask, flags);

    int q = n * DW;
    r8_init<<<(q + 255) / 256, 256, 0, stream>>>(x, mask, A, B, d_out, n, flags);

    int pb1 = (n + 3) / 4;                        // 1 row/wave upper bound
    r8_base<<<pb1, 256, 0, stream>>>(x, d_out, ents_m, meta, start_m, cnt, flags);

    int waves4 = (n + 3) / 4;                     // 4 rows/wave upper bound
    int pb4 = (waves4 + 3) / 4;
    unsigned int* src = A;
    unsigned int* dst = B;
    for (int it = 0; it < N_ITER - 1; ++it) {
        r8_prop<<<pb4, 256, 0, stream>>>(src, dst, d_out, ents_u, meta, flags);
        unsigned int* tmp = src; src = dst; dst = tmp;
    }
    r8_prop_final<<<pb4, 256, 0, stream>>>(src, d_out, ents_u, meta, flags);
}

// Round 9
// 1187.461 us; speedup vs baseline: 1.4301x; 1.4301x over previous
//
#include <hip/hip_runtime.h>

#define D 128
#define N_ITER 40
#define DW (D / 2)   // 64 packed-bf16 words per row

struct Ent9 { int c; float w; };

// flags[0]: edges 32-bit  [1]: mask odd word nz  [2]: mask word>1
// [3]: mask halfword non-float-like  [4]: mask low-halfword float-like
// [6]: x-is-bf16 votes (of 4096)  [7]: unmasked row count
// [9]: masked-col entry total      [10]: unmasked-col entry total
__device__ __forceinline__ int r9_mask_mode(const int* f) {
    if (!f[2]) return f[1] ? 1 : 2;
    if (!f[3]) return f[4] ? 3 : 1;
    return 0;
}
__device__ __forceinline__ bool r9_get_mask(const void* m, int i, int mode) {
    if (mode == 2) return ((const unsigned int*)m)[2 * (long long)i] != 0u;
    if (mode == 1) return ((const unsigned int*)m)[i] != 0u;
    if (mode == 3) return ((const unsigned short*)m)[i] != 0u;
    return ((const unsigned char*)m)[i] != 0u;
}
__device__ __forceinline__ int r9_xbf(const int* f) { return (f[6] * 2 >= 4096) ? 1 : 0; }
__device__ __forceinline__ int r9_erow(const int* e32, int e, int i, int is64) {
    return is64 ? e32[2 * (long long)i] : e32[i];
}
__device__ __forceinline__ int r9_ecol(const int* e32, int e, int i, int is64) {
    return is64 ? e32[2 * ((long long)e + i)] : e32[(long long)e + i];
}
__device__ __forceinline__ unsigned short r9_f2bf(float f) {
    unsigned int u = __float_as_uint(f);
    unsigned int r = 0x7fffu + ((u >> 16) & 1u);
    return (unsigned short)((u + r) >> 16);
}
__device__ __forceinline__ int r9_bf16ish(unsigned int h) {
    if (h == 0u) return 1;
    unsigned int ex = (h >> 7) & 0xFFu;
    return (ex >= 100u && ex <= 140u) ? 1 : 0;
}
__device__ __forceinline__ float r9_lo(unsigned int v) { return __uint_as_float(v << 16); }
__device__ __forceinline__ float r9_hi(unsigned int v) { return __uint_as_float(v & 0xFFFF0000u); }
__device__ __forceinline__ unsigned int r9_pack(float a, float b) {
    return (unsigned int)r9_f2bf(a) | ((unsigned int)r9_f2bf(b) << 16);
}
__device__ __forceinline__ long long r9_bidx(int row, int lane, int xbf) {
    return xbf ? ((long long)row * DW + lane) : ((long long)row * D + lane);
}

__global__ void r9_zero(int* p, long long cnt) {
    long long t = (long long)blockIdx.x * blockDim.x + threadIdx.x;
    long long st = (long long)gridDim.x * blockDim.x;
    for (; t < cnt; t += st) p[t] = 0;
}

__global__ void r9_detect(const int* __restrict__ edges, int e,
                          const unsigned int* __restrict__ mask, int n,
                          const unsigned int* __restrict__ x, int* __restrict__ flags) {
    __shared__ int sh_votes;
    if (threadIdx.x == 0) sh_votes = 0;
    __syncthreads();
    int t = blockIdx.x * blockDim.x + threadIdx.x;
    int stride = gridDim.x * blockDim.x;
    int f_e32 = 0, f_odd = 0, f_01 = 0, f_hw = 0, f_h0 = 0;
    for (int i = t; i < 65536; i += stride) {
        long long j = ((long long)i * e) >> 16;
        if (edges[2 * j + 1] != 0) f_e32 = 1;
    }
    int mw = n >> 2;
    for (int i = t; i < mw; i += stride) {
        unsigned int w = mask[i];
        if ((i & 1) && w) f_odd = 1;
        if (w > 1u) f_01 = 1;
        unsigned int h0 = w & 0xFFFFu, h1 = w >> 16;
        if ((h0 && h0 != 0x3F80u && h0 != 0x3C00u) ||
            (h1 && h1 != 0x3F80u && h1 != 0x3C00u)) f_hw = 1;
        if (h0 == 0x3F80u || h0 == 0x3C00u) f_h0 = 1;
    }
    long long xw = (long long)n * DW;
    int my = 0;
    for (int s = t; s < 4096; s += stride) {
        long long j = ((long long)s * xw) >> 12;
        unsigned int w = x[j];
        if (r9_bf16ish(w & 0xFFFFu) && r9_bf16ish(w >> 16)) my++;
    }
    if (my) atomicAdd(&sh_votes, my);
    if (f_e32) atomicOr(&flags[0], 1);
    if (f_odd) atomicOr(&flags[1], 1);
    if (f_01)  atomicOr(&flags[2], 1);
    if (f_hw)  atomicOr(&flags[3], 1);
    if (f_h0)  atomicOr(&flags[4], 1);
    __syncthreads();
    if (threadIdx.x == 0 && sh_votes) atomicAdd(&flags[6], sh_votes);
}

// exactly 1 atomic per edge: masked row -> deg; unmasked row -> packed cnt
// cnt[r]: high16 = masked-col count, low16 = unmasked-col count
__global__ void r9_deg_all(const int* __restrict__ edges, int e,
                           const void* __restrict__ mask, int* __restrict__ deg,
                           int* __restrict__ cnt, const int* __restrict__ flags) {
    int i = blockIdx.x * blockDim.x + threadIdx.x;
    if (i >= e) return;
    int is64 = (flags[0] == 0);
    int mm = r9_mask_mode(flags);
    int r = r9_erow(edges, e, i, is64);
    if (r9_get_mask(mask, r, mm)) { atomicAdd(&deg[r], 1); return; }
    int c = r9_ecol(edges, e, i, is64);
    atomicAdd(&cnt[r], r9_get_mask(mask, c, mm) ? 0x10000 : 1);
}

// dinv for all nodes + compacted unmasked-row list (index order preserved ~blockwise)
__global__ void r9_rows(const int* __restrict__ deg, const int* __restrict__ cnt,
                        float* __restrict__ dinv, int* __restrict__ rowlist,
                        const void* __restrict__ mask, int* __restrict__ flags, int n) {
    int i = blockIdx.x * blockDim.x + threadIdx.x;
    if (i >= n) return;
    int mm = r9_mask_mode(flags);
    bool m = r9_get_mask(mask, i, mm);
    int d;
    if (m) d = deg[i];
    else { int p = cnt[i]; d = (p >> 16) + (p & 0xFFFF); }
    dinv[i] = (d > 0) ? (1.0f / sqrtf((float)d)) : 0.0f;
    if (!m) rowlist[atomicAdd(&flags[7], 1)] = i;
}

__global__ void r9_offsets(const int* __restrict__ cnt, int* __restrict__ start_m,
                           int* __restrict__ start_u, const void* __restrict__ mask,
                           int* __restrict__ flags, int n) {
    int i = blockIdx.x * blockDim.x + threadIdx.x;
    if (i >= n) return;
    int mm = r9_mask_mode(flags);
    if (r9_get_mask(mask, i, mm)) return;
    int p = cnt[i];
    start_m[i] = atomicAdd(&flags[9], p >> 16);
    start_u[i] = atomicAdd(&flags[10], p & 0xFFFF);
}

__global__ void r9_meta(const int* __restrict__ rowlist, const int* __restrict__ start_u,
                        const int* __restrict__ cnt, int4* __restrict__ meta_u,
                        const int* __restrict__ flags) {
    int wi = blockIdx.x * blockDim.x + threadIdx.x;
    if (wi >= flags[7]) return;
    int row = rowlist[wi];
    int4 mu; mu.x = row; mu.y = start_u[row]; mu.z = cnt[row] & 0xFFFF; mu.w = 0;
    meta_u[wi] = mu;
}

__global__ void r9_fill(const int* __restrict__ edges, int e, const float* __restrict__ dinv,
                        const int* __restrict__ start_m, const int* __restrict__ start_u,
                        unsigned int* __restrict__ cur,
                        Ent9* __restrict__ ents_m, Ent9* __restrict__ ents_u,
                        const void* __restrict__ mask, const int* __restrict__ flags) {
    int i = blockIdx.x * blockDim.x + threadIdx.x;
    if (i >= e) return;
    int is64 = (flags[0] == 0);
    int mm = r9_mask_mode(flags);
    int r = r9_erow(edges, e, i, is64);
    if (r9_get_mask(mask, r, mm)) return;
    int c = r9_ecol(edges, e, i, is64);
    Ent9 en; en.c = c; en.w = dinv[r] * dinv[c];
    bool cmask = r9_get_mask(mask, c, mm);
    unsigned int ret = atomicAdd(&cur[r], cmask ? 0x10000u : 1u);
    if (cmask) ents_m[start_m[r] + (ret >> 16)] = en;
    else       ents_u[start_u[r] + (ret & 0xFFFFu)] = en;
}

// init: masked rows = x into A, B, and d_out; unmasked rows of A/B = 0
__global__ void r9_init(const void* __restrict__ x, const void* __restrict__ mask,
                        unsigned int* __restrict__ A, unsigned int* __restrict__ B,
                        void* __restrict__ out, int n, const int* __restrict__ flags) {
    int t = blockIdx.x * blockDim.x + threadIdx.x;
    if (t >= n * DW) return;
    int node = t >> 6;
    int mm = r9_mask_mode(flags);
    int xbf = r9_xbf(flags);
    bool m = r9_get_mask(mask, node, mm);
    unsigned int w = 0u;
    float2 f = make_float2(0.f, 0.f);
    if (m) {
        if (xbf) w = ((const unsigned int*)x)[t];
        else { f = ((const float2*)x)[t]; w = r9_pack(f.x, f.y); }
    }
    A[t] = w;
    B[t] = w;
    if (m) {
        if (xbf) ((unsigned int*)out)[t] = w;
        else     ((float2*)out)[t] = f;
    }
}

__device__ __forceinline__ void r9_g4(const unsigned int* __restrict__ src,
                                      const Ent9* __restrict__ ep, int i, int lane,
                                      float& ax, float& ay) {
    Ent9 a = ep[i], b = ep[i + 1], c = ep[i + 2], d = ep[i + 3];
    unsigned int va = src[(long long)a.c * DW + lane];
    unsigned int vb = src[(long long)b.c * DW + lane];
    unsigned int vc = src[(long long)c.c * DW + lane];
    unsigned int vd = src[(long long)d.c * DW + lane];
    ax = fmaf(a.w, r9_lo(va), ax); ay = fmaf(a.w, r9_hi(va), ay);
    ax = fmaf(b.w, r9_lo(vb), ax); ay = fmaf(b.w, r9_hi(vb), ay);
    ax = fmaf(c.w, r9_lo(vc), ax); ay = fmaf(c.w, r9_hi(vc), ay);
    ax = fmaf(d.w, r9_lo(vd), ax); ay = fmaf(d.w, r9_hi(vd), ay);
}
__device__ __forceinline__ void r9_g1(const unsigned int* __restrict__ src,
                                      const Ent9* __restrict__ ep, int i, int lane,
                                      float& ax, float& ay) {
    Ent9 a = ep[i];
    unsigned int va = src[(long long)a.c * DW + lane];
    ax = fmaf(a.w, r9_lo(va), ax); ay = fmaf(a.w, r9_hi(va), ay);
}

// one-time base into d_out's unmasked-row slots (dead until final iteration)
__global__ __launch_bounds__(256) void r9_base(
        const void* __restrict__ x, void* __restrict__ out,
        const Ent9* __restrict__ ents_m, const int* __restrict__ rowlist,
        const int* __restrict__ start_m, const int* __restrict__ cnt,
        const int* __restrict__ flags) {
    int wi = (blockIdx.x * blockDim.x + threadIdx.x) >> 6;
    int lane = threadIdx.x & 63;
    if (wi >= flags[7]) return;
    wi = __builtin_amdgcn_readfirstlane(wi);
    int row = __builtin_amdgcn_readfirstlane(rowlist[wi]);
    int s   = __builtin_amdgcn_readfirstlane(start_m[row]);
    int cm  = __builtin_amdgcn_readfirstlane(cnt[row]) >> 16;
    int xbf = r9_xbf(flags);
    float ax = 0.f, ay = 0.f;
    const Ent9* ep = ents_m + s;
    if (xbf) {
        const unsigned int* src = (const unsigned int*)x;
        int i = 0;
        for (; i + 4 <= cm; i += 4) r9_g4(src, ep, i, lane, ax, ay);
        for (; i < cm; ++i)         r9_g1(src, ep, i, lane, ax, ay);
    } else {
        const float2* xf = (const float2*)x;
        for (int i = 0; i < cm; ++i) {
            Ent9 en = ep[i];
            float2 v = xf[(long long)en.c * DW + lane];
            ax = fmaf(en.w, v.x, ax); ay = fmaf(en.w, v.y, ay);
        }
    }
    ((unsigned int*)out)[r9_bidx(row, lane, xbf)] = r9_pack(ax, ay);
}

// propagation: one wave handles TWO rows, interleaved gathers; base read from d_out
__global__ __launch_bounds__(256) void r9_prop(
        const unsigned int* __restrict__ src, unsigned int* __restrict__ dst,
        const void* __restrict__ outbase, const Ent9* __restrict__ ents,
        const int4* __restrict__ meta, const int* __restrict__ flags) {
    int wp = (blockIdx.x * blockDim.x + threadIdx.x) >> 6;
    int lane = threadIdx.x & 63;
    int nr = flags[7];
    int i0 = 2 * wp;
    if (i0 >= nr) return;
    wp = __builtin_amdgcn_readfirstlane(wp);
    i0 = 2 * wp;
    int i1 = i0 + 1;
    bool has1 = (i1 < nr);
    int xbf = r9_xbf(flags);
    int4 m0 = meta[i0];
    int row0 = __builtin_amdgcn_readfirstlane(m0.x);
    int s0   = __builtin_amdgcn_readfirstlane(m0.y);
    int c0   = __builtin_amdgcn_readfirstlane(m0.z);
    int row1 = row0, s1 = 0, c1 = 0;
    if (has1) {
        int4 m1 = meta[i1];
        row1 = __builtin_amdgcn_readfirstlane(m1.x);
        s1   = __builtin_amdgcn_readfirstlane(m1.y);
        c1   = __builtin_amdgcn_readfirstlane(m1.z);
    }
    const unsigned int* bp = (const unsigned int*)outbase;
    unsigned int b0 = bp[r9_bidx(row0, lane, xbf)];
    float a0x = r9_lo(b0), a0y = r9_hi(b0);
    float a1x = 0.f, a1y = 0.f;
    if (has1) {
        unsigned int b1 = bp[r9_bidx(row1, lane, xbf)];
        a1x = r9_lo(b1); a1y = r9_hi(b1);
    }
    const Ent9* e0 = ents + s0;
    const Ent9* e1 = ents + s1;
    int i = 0, j = 0;
    while (i + 4 <= c0 && j + 4 <= c1) {
        r9_g4(src, e0, i, lane, a0x, a0y);
        r9_g4(src, e1, j, lane, a1x, a1y);
        i += 4; j += 4;
    }
    for (; i + 4 <= c0; i += 4) r9_g4(src, e0, i, lane, a0x, a0y);
    for (; i < c0; ++i)         r9_g1(src, e0, i, lane, a0x, a0y);
    for (; j + 4 <= c1; j += 4) r9_g4(src, e1, j, lane, a1x, a1y);
    for (; j < c1; ++j)         r9_g1(src, e1, j, lane, a1x, a1y);
    dst[(long long)row0 * DW + lane] = r9_pack(a0x, a0y);
    if (has1) dst[(long long)row1 * DW + lane] = r9_pack(a1x, a1y);
}

// final: read base from own row of d_out, accumulate, overwrite own row of d_out
__global__ __launch_bounds__(256) void r9_prop_final(
        const unsigned int* __restrict__ src, void* __restrict__ out,
        const Ent9* __restrict__ ents, const int4* __restrict__ meta,
        const int* __restrict__ flags) {
    int wp = (blockIdx.x * blockDim.x + threadIdx.x) >> 6;
    int lane = threadIdx.x & 63;
    int nr = flags[7];
    int i0 = 2 * wp;
    if (i0 >= nr) return;
    wp = __builtin_amdgcn_readfirstlane(wp);
    i0 = 2 * wp;
    int i1 = i0 + 1;
    bool has1 = (i1 < nr);
    int xbf = r9_xbf(flags);
    int4 m0 = meta[i0];
    int row0 = __builtin_amdgcn_readfirstlane(m0.x);
    int s0   = __builtin_amdgcn_readfirstlane(m0.y);
    int c0   = __builtin_amdgcn_readfirstlane(m0.z);
    int row1 = row0, s1 = 0, c1 = 0;
    if (has1) {
        int4 m1 = meta[i1];
        row1 = __builtin_amdgcn_readfirstlane(m1.x);
        s1   = __builtin_amdgcn_readfirstlane(m1.y);
        c1   = __builtin_amdgcn_readfirstlane(m1.z);
    }
    const unsigned int* bp = (const unsigned int*)out;
    unsigned int b0 = bp[r9_bidx(row0, lane, xbf)];
    float a0x = r9_lo(b0), a0y = r9_hi(b0);
    float a1x = 0.f, a1y = 0.f;
    if (has1) {
        unsigned int b1 = bp[r9_bidx(row1, lane, xbf)];
        a1x = r9_lo(b1); a1y = r9_hi(b1);
    }
    const Ent9* e0 = ents + s0;
    const Ent9* e1 = ents + s1;
    int i = 0, j = 0;
    while (i + 4 <= c0 && j + 4 <= c1) {
        r9_g4(src, e0, i, lane, a0x, a0y);
        r9_g4(src, e1, j, lane, a1x, a1y);
        i += 4; j += 4;
    }
    for (; i + 4 <= c0; i += 4) r9_g4(src, e0, i, lane, a0x, a0y);
    for (; i < c0; ++i)         r9_g1(src, e0, i, lane, a0x, a0y);
    for (; j + 4 <= c1; j += 4) r9_g4(src, e1, j, lane, a1x, a1y);
    for (; j < c1; ++j)         r9_g1(src, e1, j, lane, a1x, a1y);
    if (xbf) {
        ((unsigned int*)out)[(long long)row0 * DW + lane] = r9_pack(a0x, a0y);
        if (has1) ((unsigned int*)out)[(long long)row1 * DW + lane] = r9_pack(a1x, a1y);
    } else {
        float2 f0; f0.x = a0x; f0.y = a0y;
        ((float2*)out)[(long long)row0 * DW + lane] = f0;
        if (has1) { float2 f1; f1.x = a1x; f1.y = a1y;
                    ((float2*)out)[(long long)row1 * DW + lane] = f1; }
    }
}

extern "C" void kernel_launch(void* const* d_in, const int* in_sizes, int n_in,
                              void* d_out, int out_size, void* d_ws, size_t ws_size,
                              hipStream_t stream) {
    const void* x    = d_in[0];
    const int* edges = (const int*)d_in[1];
    const void* mask = d_in[2];
    int n = in_sizes[0] / D;
    int e = in_sizes[1] / 2;

    // ---- workspace carve (~80 MiB at n=1e5, e=1.6e6; 100.3 MiB proven to fit) ----
    char* ws = (char*)d_ws;
    size_t off = 0;
    // zero region: flags(64) deg(n) cnt(n) cur(n)
    int* flags = (int*)(ws + off); off += 64 * sizeof(int);
    int* deg   = (int*)(ws + off); off += (size_t)n * sizeof(int);
    int* cnt   = (int*)(ws + off); off += (size_t)n * sizeof(int);
    unsigned int* cur = (unsigned int*)(ws + off); off += (size_t)n * sizeof(int);
    long long zcount = 3LL * n + 64;
    int* start_m = (int*)(ws + off);   off += (size_t)n * sizeof(int);
    int* start_u = (int*)(ws + off);   off += (size_t)n * sizeof(int);
    float* dinv  = (float*)(ws + off); off += (size_t)n * sizeof(float);
    int* rowlist = (int*)(ws + off);   off += (size_t)n * sizeof(int);
    off = (off + 255) & ~(size_t)255;
    int4* meta   = (int4*)(ws + off);  off += (size_t)n * sizeof(int4);
    Ent9* ents_m = (Ent9*)(ws + off);  off += (size_t)e * sizeof(Ent9);
    off = (off + 255) & ~(size_t)255;
    Ent9* ents_u = (Ent9*)(ws + off);  off += (size_t)e * sizeof(Ent9);
    off = (off + 255) & ~(size_t)255;
    size_t hbytes = (size_t)n * D * 2;
    unsigned int* A = (unsigned int*)(ws + off); off += hbytes;
    unsigned int* B = (unsigned int*)(ws + off); off += hbytes;

    r9_zero<<<256, 256, 0, stream>>>(flags, zcount);
    r9_detect<<<128, 256, 0, stream>>>(edges, e, (const unsigned int*)mask, n,
                                       (const unsigned int*)x, flags);
    r9_deg_all<<<(e + 255) / 256, 256, 0, stream>>>(edges, e, mask, deg, cnt, flags);
    r9_rows<<<(n + 255) / 256, 256, 0, stream>>>(deg, cnt, dinv, rowlist, mask, flags, n);
    r9_offsets<<<(n + 255) / 256, 256, 0, stream>>>(cnt, start_m, start_u, mask, flags, n);
    r9_meta<<<(n + 255) / 256, 256, 0, stream>>>(rowlist, start_u, cnt, meta, flags);
    r9_fill<<<(e + 255) / 256, 256, 0, stream>>>(edges, e, dinv, start_m, start_u,
                                                 cur, ents_m, ents_u, mask, flags);

    int q = n * DW;
    r9_init<<<(q + 255) / 256, 256, 0, stream>>>(x, mask, A, B, d_out, n, flags);

    int pb1 = (n + 3) / 4;                        // 1 row/wave upper bound
    r9_base<<<pb1, 256, 0, stream>>>(x, d_out, ents_m, rowlist, start_m, cnt, flags);

    int waves2 = (n + 1) / 2;                     // 2 rows/wave upper bound
    int pb2 = (waves2 + 3) / 4;
    unsigned int* src = A;
    unsigned int* dst = B;
    for (int it = 0; it < N_ITER - 1; ++it) {
        r9_prop<<<pb2, 256, 0, stream>>>(src, dst, d_out, ents_u, meta, flags);
        unsigned int* tmp = src; src = dst; dst = tmp;
    }
    r9_prop_final<<<pb2, 256, 0, stream>>>(src, d_out, ents_u, meta, flags);
}